// Round 16
// baseline (169.212 us; speedup 1.0000x reference)
//
#include <hip/hip_runtime.h>
#include <hip/hip_bf16.h>

// Bahdanau attention (R16) = R15 + counted-vmcnt epoch prefetch in score GEMM:
//   score epochs (2 K-tiles) are double-buffered; STAGE(e+1) issued BEFORE
//   computing epoch e; top barrier = fused "s_waitcnt vmcnt(8); s_barrier"
//   (epoch e landed, epoch e+1's 8 loads stay in flight across the barrier - T4);
//   bottom barrier = raw s_barrier (no drain). LDS 64 KB -> 2 blocks/CU.
//   Everything else identical to R15 (prep fusion, compaction, cvt_enc, ctx).

#define NB 32
#define SS 2048
#define HD 1024
#define HE 1024
#define MM (NB * SS)   // compacted (padded) row space
#define NT 32          // K-tiles = HE/32

typedef float f32x4 __attribute__((ext_vector_type(4)));
typedef short bf16x8 __attribute__((ext_vector_type(8)));
typedef short short4v __attribute__((ext_vector_type(4)));

static __device__ __forceinline__ short f2bf(float f) {
    union { __hip_bfloat16 h; short s; } u;
    u.h = __float2bfloat16(f);
    return u.s;
}
static __device__ __forceinline__ float bf2f(short s) {
    union { float f; unsigned u; } u;
    u.u = ((unsigned)(unsigned short)s) << 16;
    return u.f;
}

static __device__ __forceinline__ void gload16(const void* g, const void* l) {
    __builtin_amdgcn_global_load_lds(
        (const __attribute__((address_space(1))) void*)(uintptr_t)(g),
        (__attribute__((address_space(3))) void*)(unsigned)(uintptr_t)(l),
        16, 0, 0);
}

// ---------------- fused prep: compact | qproj | cvt_wk ----------------
__global__ __launch_bounds__(256) void prep_kernel(const int* __restrict__ mask,
                                                   const float* __restrict__ dh,
                                                   const float* __restrict__ Wq,
                                                   const float* __restrict__ Wk,
                                                   int* __restrict__ idx,
                                                   int* __restrict__ cnt,
                                                   float* __restrict__ q,
                                                   short* __restrict__ wkb) {
    const int bid  = blockIdx.x;
    const int tid  = threadIdx.x;
    const int wid  = tid >> 6;
    const int lane = tid & 63;

    if (bid < 8) {
        const int b = bid * 4 + wid;
        int base = 0;
        for (int s0 = 0; s0 < SS; s0 += 64) {
            const int m = mask[b * SS + s0 + lane];
            const unsigned long long bal = __ballot(m != 0);
            const int rank = __popcll(bal & ((1ull << lane) - 1ull));
            if (m) idx[b * SS + base + rank] = s0 + lane;
            base += (int)__popcll(bal);
        }
        if (lane == 0) cnt[b] = base;
        for (int j = base + lane; j < SS; j += 64) idx[b * SS + j] = 0;
    } else if (bid < 264) {
        const int d = (bid - 8) * 4 + wid;
        const float* wrow = Wq + (long)d * HD + lane * 16;
        f32x4 w0 = *(const f32x4*)(wrow + 0);
        f32x4 w1 = *(const f32x4*)(wrow + 4);
        f32x4 w2 = *(const f32x4*)(wrow + 8);
        f32x4 w3 = *(const f32x4*)(wrow + 12);
        for (int b = 0; b < NB; ++b) {
            const float* drow = dh + b * HD + lane * 16;
            f32x4 d0 = *(const f32x4*)(drow + 0);
            f32x4 d1 = *(const f32x4*)(drow + 4);
            f32x4 d2 = *(const f32x4*)(drow + 8);
            f32x4 d3 = *(const f32x4*)(drow + 12);
            f32x4 s4 = w0 * d0 + w1 * d1 + w2 * d2 + w3 * d3;
            float dot = s4[0] + s4[1] + s4[2] + s4[3];
            #pragma unroll
            for (int off = 32; off > 0; off >>= 1)
                dot += __shfl_xor(dot, off, 64);
            if (lane == 0) q[b * HD + d] = dot;
        }
    } else {
        const int i = (bid - 264) * 256 + tid;
        const f32x4 a = *(const f32x4*)(Wk + (long)i * 8);
        const f32x4 b = *(const f32x4*)(Wk + (long)i * 8 + 4);
        bf16x8 o;
        o[0] = f2bf(a[0]); o[1] = f2bf(a[1]); o[2] = f2bf(a[2]); o[3] = f2bf(a[3]);
        o[4] = f2bf(b[0]); o[5] = f2bf(b[1]); o[6] = f2bf(b[2]); o[7] = f2bf(b[3]);
        *(bf16x8*)(wkb + (long)i * 8) = o;
    }
}

// ---------------- gather + cvt enc rows -> compacted bf16, zero-pad to 128 ----------------
__global__ __launch_bounds__(256) void cvt_enc_kernel(const float* __restrict__ enc,
                                                      const int* __restrict__ idx,
                                                      const int* __restrict__ cnt,
                                                      short* __restrict__ encb) {
    const int b  = blockIdx.x >> 7;
    const int j0 = (blockIdx.x & 127) * 16;
    const int n  = cnt[b];
    const int nr = (n + 127) & ~127;
    if (j0 >= nr) return;
    const int j  = j0 + (threadIdx.x >> 4);
    const int c0 = (threadIdx.x & 15) * 8;
    short* dst = encb + ((long)b * SS + j) * HE + c0;
    if (j < n) {
        const float* src = enc + ((long)b * SS + idx[b * SS + j]) * HE + c0;
        #pragma unroll
        for (int u = 0; u < 8; ++u) {
            const f32x4 x = *(const f32x4*)(src + u * 128);
            const f32x4 y = *(const f32x4*)(src + u * 128 + 4);
            bf16x8 o;
            o[0] = f2bf(x[0]); o[1] = f2bf(x[1]); o[2] = f2bf(x[2]); o[3] = f2bf(x[3]);
            o[4] = f2bf(y[0]); o[5] = f2bf(y[1]); o[6] = f2bf(y[2]); o[7] = f2bf(y[3]);
            *(bf16x8*)(dst + u * 128) = o;
        }
    } else {
        const bf16x8 z = (bf16x8){0,0,0,0,0,0,0,0};
        #pragma unroll
        for (int u = 0; u < 8; ++u) *(bf16x8*)(dst + u * 128) = z;
    }
}

// ---------------- score GEMM: 128x128, 4 waves, epoch-prefetch + counted vmcnt ----------------
__global__ __launch_bounds__(256, 2) void score_mfma_kernel(const short* __restrict__ encb,
                                                            const short* __restrict__ wkb,
                                                            const float* __restrict__ qv,
                                                            const float* __restrict__ ven,
                                                            const int* __restrict__ cnt,
                                                            float* __restrict__ sp) {
    __shared__ __align__(16) short As[4 * 4096];   // [buf][ktile] 2x2x8KB = 32 KB
    __shared__ __align__(16) short Bs[4 * 4096];

    // XCD swizzle: 8 sibling N-tiles of an M-tile on one XCD (A L2 reuse)
    const int bid   = blockIdx.x;
    const int xcd   = bid & 7;
    const int slot  = bid >> 3;
    const int mtile = xcd * 64 + (slot >> 3);
    const int nt    = slot & 7;

    const int bb   = mtile >> 4;
    const int tile = mtile & 15;
    if (tile * 128 >= cnt[bb]) return;

    const int tid  = threadIdx.x;
    const int lane = tid & 63;
    const int wid  = tid >> 6;
    const int wr   = wid >> 1;
    const int wc   = wid & 1;
    const long mbase = (long)bb * SS + tile * 128;
    const int  nbase = nt * 128;

    f32x4 acc[4][4];
    #pragma unroll
    for (int m = 0; m < 4; ++m)
        #pragma unroll
        for (int n = 0; n < 4; ++n)
            acc[m][n] = (f32x4){0.f, 0.f, 0.f, 0.f};

    const short* ag0 = encb + (mbase + (tid >> 2)) * (long)HE + (tid & 3) * 8;
    const short* ag1 = ag0 + 64 * (long)HE;
    const short* bg0 = wkb + ((long)(nbase + (tid >> 2))) * HE + (tid & 3) * 8;
    const short* bg1 = bg0 + 64 * (long)HE;

    const int frow = lane & 15;
    const int kby  = (lane >> 4) * 16;

    #define ABASE(BUF, T) ((char*)As + ((BUF) * 2 + (T)) * 8192)
    #define BBASE(BUF, T) ((char*)Bs + ((BUF) * 2 + (T)) * 8192)

    // stage epoch E (K-tiles 2E, 2E+1) into buffer BUF: 8 gloads
    #define STAGE(BUF, E)                                            \
        do {                                                         \
            const int ko0_ = (E) * 64;                               \
            const int ko1_ = ko0_ + 32;                              \
            gload16(ag0 + ko0_, ABASE(BUF, 0) + wid * 1024);         \
            gload16(ag1 + ko0_, ABASE(BUF, 0) + 4096 + wid * 1024);  \
            gload16(bg0 + ko0_, BBASE(BUF, 0) + wid * 1024);         \
            gload16(bg1 + ko0_, BBASE(BUF, 0) + 4096 + wid * 1024);  \
            gload16(ag0 + ko1_, ABASE(BUF, 1) + wid * 1024);         \
            gload16(ag1 + ko1_, ABASE(BUF, 1) + 4096 + wid * 1024);  \
            gload16(bg0 + ko1_, BBASE(BUF, 1) + wid * 1024);         \
            gload16(bg1 + ko1_, BBASE(BUF, 1) + 4096 + wid * 1024);  \
        } while (0)

    #define COMPUTE(BUF, T)                                                      \
        do {                                                                     \
            bf16x8 af[4], bfr[4];                                                \
            _Pragma("unroll")                                                    \
            for (int m = 0; m < 4; ++m)                                          \
                af[m] = *(const bf16x8*)(ABASE(BUF, T)                           \
                          + (wr * 64 + m * 16 + frow) * 64 + kby);               \
            _Pragma("unroll")                                                    \
            for (int n = 0; n < 4; ++n)                                          \
                bfr[n] = *(const bf16x8*)(BBASE(BUF, T)                          \
                          + (wc * 64 + n * 16 + frow) * 64 + kby);               \
            _Pragma("unroll")                                                    \
            for (int m = 0; m < 4; ++m)                                          \
                _Pragma("unroll")                                                \
                for (int n = 0; n < 4; ++n)                                      \
                    acc[m][n] = __builtin_amdgcn_mfma_f32_16x16x32_bf16(         \
                        af[m], bfr[n], acc[m][n], 0, 0, 0);                      \
        } while (0)

    // prologue: stage epoch 0 into buf 0
    STAGE(0, 0);

    // 16 epochs; STAGE(e+1) issued BEFORE computing e; counted vmcnt across barrier
    for (int e = 0; e < 16; ++e) {
        const int cur = e & 1;
        if (e < 15) {
            STAGE(cur ^ 1, e + 1);
            // epoch e's 8 loads are the oldest -> done at vmcnt(8);
            // epoch e+1's 8 stay in flight across the barrier (T4).
            asm volatile("s_waitcnt vmcnt(8)\n\ts_barrier" ::: "memory");
        } else {
            asm volatile("s_waitcnt vmcnt(0)\n\ts_barrier" ::: "memory");
        }
        COMPUTE(cur, 0);
        COMPUTE(cur, 1);
        // WAR fence only: ds_reads of buf[cur] completed (consumed by MFMA);
        // next iteration's STAGE overwrites buf[cur] after this join.
        asm volatile("s_barrier" ::: "memory");
    }
    #undef COMPUTE
    #undef STAGE
    #undef ABASE
    #undef BBASE

    float qq[4], vv[4];
    #pragma unroll
    for (int n = 0; n < 4; ++n) {
        const int c = nbase + wc * 64 + n * 16 + frow;
        qq[n] = qv[bb * HD + c];
        vv[n] = ven[c];
    }
    float p[4][4];
    #pragma unroll
    for (int m = 0; m < 4; ++m) {
        #pragma unroll
        for (int rg = 0; rg < 4; ++rg) {
            float s = 0.f;
            #pragma unroll
            for (int n = 0; n < 4; ++n) {
                const float x = acc[m][n][rg] + qq[n];
                const float e = __expf(2.f * x);
                const float t = 1.f - 2.f * __builtin_amdgcn_rcpf(e + 1.f);
                s += vv[n] * t;
            }
            #pragma unroll
            for (int msk = 1; msk <= 8; msk <<= 1)
                s += __shfl_xor(s, msk, 64);
            p[m][rg] = s;
        }
    }
    if ((lane & 15) == 0) {
        const int g = lane >> 4;
        float* dst = sp + (long)(nt * 2 + wc) * MM;
        #pragma unroll
        for (int m = 0; m < 4; ++m)
            #pragma unroll
            for (int rg = 0; rg < 4; ++rg)
                dst[mbase + wr * 64 + m * 16 + g * 4 + rg] = p[m][rg];
    }
}

// ---------------- softmax over compacted domain; zero + scatter to attn ----------------
__global__ __launch_bounds__(256) void softmax_kernel(const float* __restrict__ sp,
                                                      const int* __restrict__ idx,
                                                      const int* __restrict__ cnt,
                                                      float* __restrict__ attn,
                                                      float* __restrict__ wcomp) {
    const int b = blockIdx.x;
    const int tid = threadIdx.x;
    const int lane = tid & 63;
    const int wid = tid >> 6;
    const int n = cnt[b];
    #pragma unroll
    for (int i = 0; i < 8; ++i)
        attn[b * SS + tid + i * 256] = 0.f;
    __shared__ float red[4];
    float sc[8];
    float mx = -3.0e38f;
    #pragma unroll
    for (int i = 0; i < 8; ++i) {
        const int j = tid + i * 256;
        float v = -3.0e38f;
        if (j < n) {
            v = 0.f;
            #pragma unroll
            for (int k = 0; k < 16; ++k)
                v += sp[(long)k * MM + b * SS + j];
        }
        sc[i] = v;
        mx = fmaxf(mx, v);
    }
    #pragma unroll
    for (int off = 32; off > 0; off >>= 1)
        mx = fmaxf(mx, __shfl_xor(mx, off, 64));
    if (lane == 0) red[wid] = mx;
    __syncthreads();
    mx = fmaxf(fmaxf(red[0], red[1]), fmaxf(red[2], red[3]));
    __syncthreads();
    float sum = 0.f;
    #pragma unroll
    for (int i = 0; i < 8; ++i) {
        const float e = (sc[i] > -1.0e38f) ? __expf(sc[i] - mx) : 0.f;
        sc[i] = e;
        sum += e;
    }
    #pragma unroll
    for (int off = 32; off > 0; off >>= 1)
        sum += __shfl_xor(sum, off, 64);
    if (lane == 0) red[wid] = sum;
    __syncthreads();
    sum = red[0] + red[1] + red[2] + red[3];
    const float inv = 1.f / sum;
    #pragma unroll
    for (int i = 0; i < 8; ++i) {
        const int j = tid + i * 256;
        const float w = sc[i] * inv;
        wcomp[b * SS + j] = w;
        if (j < n) attn[b * SS + idx[b * SS + j]] = w;
    }
}

// ---------------- context over compacted bf16 rows ----------------
__global__ __launch_bounds__(256) void ctx_partial_kernel(const short* __restrict__ encb,
                                                          const float* __restrict__ wcomp,
                                                          const int* __restrict__ cnt,
                                                          float* __restrict__ cp) {
    const int b = blockIdx.x >> 5;
    const int chunk = blockIdx.x & 31;
    const int tid = threadIdx.x;
    float* dst = cp + ((long)(b * 32 + chunk)) * HE + tid * 4;
    if (chunk * 64 >= cnt[b]) {
        *(f32x4*)dst = (f32x4){0.f, 0.f, 0.f, 0.f};
        return;
    }
    const short* ep = encb + ((long)b * SS + chunk * 64) * HE + tid * 4;
    const float* ap = wcomp + b * SS + chunk * 64;
    f32x4 acc = (f32x4){0.f, 0.f, 0.f, 0.f};
    #pragma unroll 4
    for (int s = 0; s < 64; ++s) {
        const float w = ap[s];
        const short4v v = *(const short4v*)(ep + (long)s * HE);
        acc[0] += w * bf2f(v[0]);
        acc[1] += w * bf2f(v[1]);
        acc[2] += w * bf2f(v[2]);
        acc[3] += w * bf2f(v[3]);
    }
    *(f32x4*)dst = acc;
}

__global__ __launch_bounds__(256) void ctx_reduce_kernel(const float* __restrict__ cp,
                                                         float* __restrict__ out) {
    const int o = blockIdx.x * 256 + threadIdx.x;
    const int b = o >> 10;
    const int e = o & 1023;
    float s = 0.f;
    #pragma unroll
    for (int c = 0; c < 32; ++c)
        s += cp[((long)(b * 32 + c)) * HE + e];
    out[o] = s;
}

extern "C" void kernel_launch(void* const* d_in, const int* in_sizes, int n_in,
                              void* d_out, int out_size, void* d_ws, size_t ws_size,
                              hipStream_t stream) {
    const float* dh   = (const float*)d_in[0];
    const float* enc  = (const float*)d_in[1];
    const int*   mask = (const int*)d_in[2];
    const float* Wq   = (const float*)d_in[3];
    const float* Wk   = (const float*)d_in[4];
    const float* Ve   = (const float*)d_in[5];

    float* out  = (float*)d_out;
    float* ctx  = out;
    float* attn = out + NB * HD;

    float* ws    = (float*)d_ws;
    float* wq_   = ws;                            // 32768 f
    float* sp    = ws + 32768;                    // 16 * 65536 f (4 MB)
    float* cp    = sp + 16 * (long)MM;            // 32*32*1024 f (4 MB)
    short* wkb   = (short*)(cp + 32 * 32 * HE);   // 1M bf16 (2 MB)
    float* wcomp = (float*)(wkb + (long)HD * HE); // 65536 f
    int*   idx   = (int*)(wcomp + MM);            // 65536 i
    int*   cnt   = idx + MM;                      // 32 i (+pad)
    short* encb  = (short*)(cnt + 64);            // 67.1M bf16 (128 MB)

    prep_kernel<<<776, 256, 0, stream>>>(mask, dh, Wq, Wk, idx, cnt, wq_, wkb);
    cvt_enc_kernel<<<NB * 128, 256, 0, stream>>>(enc, idx, cnt, encb);
    score_mfma_kernel<<<4096, 256, 0, stream>>>(encb, wkb, wq_, Ve, cnt, sp);
    softmax_kernel<<<NB, 256, 0, stream>>>(sp, idx, cnt, attn, wcomp);
    ctx_partial_kernel<<<1024, 256, 0, stream>>>(encb, wcomp, cnt, cp);
    ctx_reduce_kernel<<<128, 256, 0, stream>>>(cp, ctx);
}

// Round 17
// 167.535 us; speedup vs baseline: 1.0100x; 1.0100x over previous
//
#include <hip/hip_runtime.h>
#include <hip/hip_bf16.h>

// Bahdanau attention (R17) = R15 (best: 164.2us) with score epochs widened to
// 3 K-tiles (11 epochs instead of 16; LDS 48KB keeps 3 blocks/CU).
//   prep = compact | qproj | cvt_wk (fused heterogeneous kernel)
//   cvt_enc: gather unmasked rows -> compacted bf16 encb (zero-pad to 128)
//   score: m97-style 128x128 bf16 GEMM over compacted rows, 4 waves, acc[4][4],
//          A+B via global_load_lds, 3 K-tiles per sync epoch, 3 blocks/CU,
//          XCD swizzle, fused tanh/v-dot epilogue
//   softmax over compacted domain (zeroes attn, scatters weights)
//   ctx over compacted bf16 rows.

#define NB 32
#define SS 2048
#define HD 1024
#define HE 1024
#define MM (NB * SS)   // compacted (padded) row space
#define NT 32          // K-tiles = HE/32

typedef float f32x4 __attribute__((ext_vector_type(4)));
typedef short bf16x8 __attribute__((ext_vector_type(8)));
typedef short short4v __attribute__((ext_vector_type(4)));

static __device__ __forceinline__ short f2bf(float f) {
    union { __hip_bfloat16 h; short s; } u;
    u.h = __float2bfloat16(f);
    return u.s;
}
static __device__ __forceinline__ float bf2f(short s) {
    union { float f; unsigned u; } u;
    u.u = ((unsigned)(unsigned short)s) << 16;
    return u.f;
}

static __device__ __forceinline__ void gload16(const void* g, const void* l) {
    __builtin_amdgcn_global_load_lds(
        (const __attribute__((address_space(1))) void*)(uintptr_t)(g),
        (__attribute__((address_space(3))) void*)(unsigned)(uintptr_t)(l),
        16, 0, 0);
}

// ---------------- fused prep: compact | qproj | cvt_wk ----------------
__global__ __launch_bounds__(256) void prep_kernel(const int* __restrict__ mask,
                                                   const float* __restrict__ dh,
                                                   const float* __restrict__ Wq,
                                                   const float* __restrict__ Wk,
                                                   int* __restrict__ idx,
                                                   int* __restrict__ cnt,
                                                   float* __restrict__ q,
                                                   short* __restrict__ wkb) {
    const int bid  = blockIdx.x;
    const int tid  = threadIdx.x;
    const int wid  = tid >> 6;
    const int lane = tid & 63;

    if (bid < 8) {
        const int b = bid * 4 + wid;
        int base = 0;
        for (int s0 = 0; s0 < SS; s0 += 64) {
            const int m = mask[b * SS + s0 + lane];
            const unsigned long long bal = __ballot(m != 0);
            const int rank = __popcll(bal & ((1ull << lane) - 1ull));
            if (m) idx[b * SS + base + rank] = s0 + lane;
            base += (int)__popcll(bal);
        }
        if (lane == 0) cnt[b] = base;
        for (int j = base + lane; j < SS; j += 64) idx[b * SS + j] = 0;
    } else if (bid < 264) {
        const int d = (bid - 8) * 4 + wid;
        const float* wrow = Wq + (long)d * HD + lane * 16;
        f32x4 w0 = *(const f32x4*)(wrow + 0);
        f32x4 w1 = *(const f32x4*)(wrow + 4);
        f32x4 w2 = *(const f32x4*)(wrow + 8);
        f32x4 w3 = *(const f32x4*)(wrow + 12);
        for (int b = 0; b < NB; ++b) {
            const float* drow = dh + b * HD + lane * 16;
            f32x4 d0 = *(const f32x4*)(drow + 0);
            f32x4 d1 = *(const f32x4*)(drow + 4);
            f32x4 d2 = *(const f32x4*)(drow + 8);
            f32x4 d3 = *(const f32x4*)(drow + 12);
            f32x4 s4 = w0 * d0 + w1 * d1 + w2 * d2 + w3 * d3;
            float dot = s4[0] + s4[1] + s4[2] + s4[3];
            #pragma unroll
            for (int off = 32; off > 0; off >>= 1)
                dot += __shfl_xor(dot, off, 64);
            if (lane == 0) q[b * HD + d] = dot;
        }
    } else {
        const int i = (bid - 264) * 256 + tid;
        const f32x4 a = *(const f32x4*)(Wk + (long)i * 8);
        const f32x4 b = *(const f32x4*)(Wk + (long)i * 8 + 4);
        bf16x8 o;
        o[0] = f2bf(a[0]); o[1] = f2bf(a[1]); o[2] = f2bf(a[2]); o[3] = f2bf(a[3]);
        o[4] = f2bf(b[0]); o[5] = f2bf(b[1]); o[6] = f2bf(b[2]); o[7] = f2bf(b[3]);
        *(bf16x8*)(wkb + (long)i * 8) = o;
    }
}

// ---------------- gather + cvt enc rows -> compacted bf16, zero-pad to 128 ----------------
__global__ __launch_bounds__(256) void cvt_enc_kernel(const float* __restrict__ enc,
                                                      const int* __restrict__ idx,
                                                      const int* __restrict__ cnt,
                                                      short* __restrict__ encb) {
    const int b  = blockIdx.x >> 7;
    const int j0 = (blockIdx.x & 127) * 16;
    const int n  = cnt[b];
    const int nr = (n + 127) & ~127;
    if (j0 >= nr) return;
    const int j  = j0 + (threadIdx.x >> 4);
    const int c0 = (threadIdx.x & 15) * 8;
    short* dst = encb + ((long)b * SS + j) * HE + c0;
    if (j < n) {
        const float* src = enc + ((long)b * SS + idx[b * SS + j]) * HE + c0;
        #pragma unroll
        for (int u = 0; u < 8; ++u) {
            const f32x4 x = *(const f32x4*)(src + u * 128);
            const f32x4 y = *(const f32x4*)(src + u * 128 + 4);
            bf16x8 o;
            o[0] = f2bf(x[0]); o[1] = f2bf(x[1]); o[2] = f2bf(x[2]); o[3] = f2bf(x[3]);
            o[4] = f2bf(y[0]); o[5] = f2bf(y[1]); o[6] = f2bf(y[2]); o[7] = f2bf(y[3]);
            *(bf16x8*)(dst + u * 128) = o;
        }
    } else {
        const bf16x8 z = (bf16x8){0,0,0,0,0,0,0,0};
        #pragma unroll
        for (int u = 0; u < 8; ++u) *(bf16x8*)(dst + u * 128) = z;
    }
}

// ---------------- score GEMM: 128x128, 4 waves, 3 K-tiles per epoch ----------------
__global__ __launch_bounds__(256, 3) void score_mfma_kernel(const short* __restrict__ encb,
                                                            const short* __restrict__ wkb,
                                                            const float* __restrict__ qv,
                                                            const float* __restrict__ ven,
                                                            const int* __restrict__ cnt,
                                                            float* __restrict__ sp) {
    __shared__ __align__(16) short As[3][4096];   // three 8 KB A K-subtiles (24 KB)
    __shared__ __align__(16) short Bs[3][4096];   // three 8 KB B K-subtiles (24 KB)

    // XCD swizzle: 8 sibling N-tiles of an M-tile on one XCD (A L2 reuse)
    const int bid   = blockIdx.x;
    const int xcd   = bid & 7;
    const int slot  = bid >> 3;                 // 0..511
    const int mtile = xcd * 64 + (slot >> 3);   // 0..511
    const int nt    = slot & 7;                 // 0..7

    const int bb   = mtile >> 4;
    const int tile = mtile & 15;
    if (tile * 128 >= cnt[bb]) return;          // masked tail tile: dead

    const int tid  = threadIdx.x;
    const int lane = tid & 63;
    const int wid  = tid >> 6;
    const int wr   = wid >> 1;
    const int wc   = wid & 1;
    const long mbase = (long)bb * SS + tile * 128;
    const int  nbase = nt * 128;

    f32x4 acc[4][4];
    #pragma unroll
    for (int m = 0; m < 4; ++m)
        #pragma unroll
        for (int n = 0; n < 4; ++n)
            acc[m][n] = (f32x4){0.f, 0.f, 0.f, 0.f};

    const short* ag0 = encb + (mbase + (tid >> 2)) * (long)HE + (tid & 3) * 8;
    const short* ag1 = ag0 + 64 * (long)HE;
    const short* bg0 = wkb + ((long)(nbase + (tid >> 2))) * HE + (tid & 3) * 8;
    const short* bg1 = bg0 + 64 * (long)HE;

    const int frow = lane & 15;
    const int kby  = (lane >> 4) * 16;

    #define STAGE1(T, KT)                                            \
        do {                                                         \
            const int ko_ = (KT) * 32;                               \
            gload16(ag0 + ko_, (char*)As[T] + wid * 1024);           \
            gload16(ag1 + ko_, (char*)As[T] + 4096 + wid * 1024);    \
            gload16(bg0 + ko_, (char*)Bs[T] + wid * 1024);           \
            gload16(bg1 + ko_, (char*)Bs[T] + 4096 + wid * 1024);    \
        } while (0)

    #define COMPUTE(T)                                                           \
        do {                                                                     \
            bf16x8 af[4], bfr[4];                                                \
            _Pragma("unroll")                                                    \
            for (int m = 0; m < 4; ++m)                                          \
                af[m] = *(const bf16x8*)((const char*)As[T]                      \
                          + (wr * 64 + m * 16 + frow) * 64 + kby);               \
            _Pragma("unroll")                                                    \
            for (int n = 0; n < 4; ++n)                                          \
                bfr[n] = *(const bf16x8*)((const char*)Bs[T]                     \
                          + (wc * 64 + n * 16 + frow) * 64 + kby);               \
            _Pragma("unroll")                                                    \
            for (int m = 0; m < 4; ++m)                                          \
                _Pragma("unroll")                                                \
                for (int n = 0; n < 4; ++n)                                      \
                    acc[m][n] = __builtin_amdgcn_mfma_f32_16x16x32_bf16(         \
                        af[m], bfr[n], acc[m][n], 0, 0, 0);                      \
        } while (0)

    // 10 epochs of 3 K-tiles + 1 tail epoch of 2 (NT = 32 = 10*3 + 2)
    for (int e = 0; e < 10; ++e) {
        const int kt0 = e * 3;
        STAGE1(0, kt0);
        STAGE1(1, kt0 + 1);
        STAGE1(2, kt0 + 2);
        __syncthreads();        // drains the 12 gloads, joins waves
        COMPUTE(0);
        COMPUTE(1);
        COMPUTE(2);
        __syncthreads();        // LDS reads done before next epoch overwrites
    }
    STAGE1(0, 30);
    STAGE1(1, 31);
    __syncthreads();
    COMPUTE(0);
    COMPUTE(1);
    #undef COMPUTE
    #undef STAGE1

    // epilogue: partial score over this wave's 64 cols; C/D: col=lane&15, row=(lane>>4)*4+reg
    float qq[4], vv[4];
    #pragma unroll
    for (int n = 0; n < 4; ++n) {
        const int c = nbase + wc * 64 + n * 16 + frow;
        qq[n] = qv[bb * HD + c];
        vv[n] = ven[c];
    }
    float p[4][4];
    #pragma unroll
    for (int m = 0; m < 4; ++m) {
        #pragma unroll
        for (int rg = 0; rg < 4; ++rg) {
            float s = 0.f;
            #pragma unroll
            for (int n = 0; n < 4; ++n) {
                const float x = acc[m][n][rg] + qq[n];
                const float e = __expf(2.f * x);
                const float t = 1.f - 2.f * __builtin_amdgcn_rcpf(e + 1.f);
                s += vv[n] * t;
            }
            #pragma unroll
            for (int msk = 1; msk <= 8; msk <<= 1)
                s += __shfl_xor(s, msk, 64);
            p[m][rg] = s;
        }
    }
    if ((lane & 15) == 0) {
        const int g = lane >> 4;
        float* dst = sp + (long)(nt * 2 + wc) * MM;
        #pragma unroll
        for (int m = 0; m < 4; ++m)
            #pragma unroll
            for (int rg = 0; rg < 4; ++rg)
                dst[mbase + wr * 64 + m * 16 + g * 4 + rg] = p[m][rg];
    }
}

// ---------------- softmax over compacted domain; zero + scatter to attn ----------------
__global__ __launch_bounds__(256) void softmax_kernel(const float* __restrict__ sp,
                                                      const int* __restrict__ idx,
                                                      const int* __restrict__ cnt,
                                                      float* __restrict__ attn,
                                                      float* __restrict__ wcomp) {
    const int b = blockIdx.x;
    const int tid = threadIdx.x;
    const int lane = tid & 63;
    const int wid = tid >> 6;
    const int n = cnt[b];
    #pragma unroll
    for (int i = 0; i < 8; ++i)
        attn[b * SS + tid + i * 256] = 0.f;
    __shared__ float red[4];
    float sc[8];
    float mx = -3.0e38f;
    #pragma unroll
    for (int i = 0; i < 8; ++i) {
        const int j = tid + i * 256;
        float v = -3.0e38f;
        if (j < n) {
            v = 0.f;
            #pragma unroll
            for (int k = 0; k < 16; ++k)
                v += sp[(long)k * MM + b * SS + j];
        }
        sc[i] = v;
        mx = fmaxf(mx, v);
    }
    #pragma unroll
    for (int off = 32; off > 0; off >>= 1)
        mx = fmaxf(mx, __shfl_xor(mx, off, 64));
    if (lane == 0) red[wid] = mx;
    __syncthreads();
    mx = fmaxf(fmaxf(red[0], red[1]), fmaxf(red[2], red[3]));
    __syncthreads();
    float sum = 0.f;
    #pragma unroll
    for (int i = 0; i < 8; ++i) {
        const float e = (sc[i] > -1.0e38f) ? __expf(sc[i] - mx) : 0.f;
        sc[i] = e;
        sum += e;
    }
    #pragma unroll
    for (int off = 32; off > 0; off >>= 1)
        sum += __shfl_xor(sum, off, 64);
    if (lane == 0) red[wid] = sum;
    __syncthreads();
    sum = red[0] + red[1] + red[2] + red[3];
    const float inv = 1.f / sum;
    #pragma unroll
    for (int i = 0; i < 8; ++i) {
        const int j = tid + i * 256;
        const float w = sc[i] * inv;
        wcomp[b * SS + j] = w;
        if (j < n) attn[b * SS + idx[b * SS + j]] = w;
    }
}

// ---------------- context over compacted bf16 rows ----------------
__global__ __launch_bounds__(256) void ctx_partial_kernel(const short* __restrict__ encb,
                                                          const float* __restrict__ wcomp,
                                                          const int* __restrict__ cnt,
                                                          float* __restrict__ cp) {
    const int b = blockIdx.x >> 5;
    const int chunk = blockIdx.x & 31;
    const int tid = threadIdx.x;
    float* dst = cp + ((long)(b * 32 + chunk)) * HE + tid * 4;
    if (chunk * 64 >= cnt[b]) {
        *(f32x4*)dst = (f32x4){0.f, 0.f, 0.f, 0.f};
        return;
    }
    const short* ep = encb + ((long)b * SS + chunk * 64) * HE + tid * 4;
    const float* ap = wcomp + b * SS + chunk * 64;
    f32x4 acc = (f32x4){0.f, 0.f, 0.f, 0.f};
    #pragma unroll 4
    for (int s = 0; s < 64; ++s) {
        const float w = ap[s];
        const short4v v = *(const short4v*)(ep + (long)s * HE);
        acc[0] += w * bf2f(v[0]);
        acc[1] += w * bf2f(v[1]);
        acc[2] += w * bf2f(v[2]);
        acc[3] += w * bf2f(v[3]);
    }
    *(f32x4*)dst = acc;
}

__global__ __launch_bounds__(256) void ctx_reduce_kernel(const float* __restrict__ cp,
                                                         float* __restrict__ out) {
    const int o = blockIdx.x * 256 + threadIdx.x;
    const int b = o >> 10;
    const int e = o & 1023;
    float s = 0.f;
    #pragma unroll
    for (int c = 0; c < 32; ++c)
        s += cp[((long)(b * 32 + c)) * HE + e];
    out[o] = s;
}

extern "C" void kernel_launch(void* const* d_in, const int* in_sizes, int n_in,
                              void* d_out, int out_size, void* d_ws, size_t ws_size,
                              hipStream_t stream) {
    const float* dh   = (const float*)d_in[0];
    const float* enc  = (const float*)d_in[1];
    const int*   mask = (const int*)d_in[2];
    const float* Wq   = (const float*)d_in[3];
    const float* Wk   = (const float*)d_in[4];
    const float* Ve   = (const float*)d_in[5];

    float* out  = (float*)d_out;
    float* ctx  = out;
    float* attn = out + NB * HD;

    float* ws    = (float*)d_ws;
    float* wq_   = ws;                            // 32768 f
    float* sp    = ws + 32768;                    // 16 * 65536 f (4 MB)
    float* cp    = sp + 16 * (long)MM;            // 32*32*1024 f (4 MB)
    short* wkb   = (short*)(cp + 32 * 32 * HE);   // 1M bf16 (2 MB)
    float* wcomp = (float*)(wkb + (long)HD * HE); // 65536 f
    int*   idx   = (int*)(wcomp + MM);            // 65536 i
    int*   cnt   = idx + MM;                      // 32 i (+pad)
    short* encb  = (short*)(cnt + 64);            // 67.1M bf16 (128 MB)

    prep_kernel<<<776, 256, 0, stream>>>(mask, dh, Wq, Wk, idx, cnt, wq_, wkb);
    cvt_enc_kernel<<<NB * 128, 256, 0, stream>>>(enc, idx, cnt, encb);
    score_mfma_kernel<<<4096, 256, 0, stream>>>(encb, wkb, wq_, Ve, cnt, sp);
    softmax_kernel<<<NB, 256, 0, stream>>>(sp, idx, cnt, attn, wcomp);
    ctx_partial_kernel<<<1024, 256, 0, stream>>>(encb, wcomp, cnt, cp);
    ctx_reduce_kernel<<<128, 256, 0, stream>>>(cp, ctx);
}

// Round 18
// 165.320 us; speedup vs baseline: 1.0235x; 1.0134x over previous
//
#include <hip/hip_runtime.h>
#include <hip/hip_bf16.h>

// Bahdanau attention (R18) = R15 (best: 164.2us) with prep FUSED into cvt_enc:
//   front_kernel: blocks 0-4095   = cvt_enc with per-block self-compaction scan
//                 blocks 4096-4351 = qproj
//                 blocks 4352-4863 = cvt_wk
//   (removes the serial prep->cvt_enc boundary; scan blocks publish idx/cnt)
//   score: m97-style 128x128 bf16 GEMM, 4 waves, 2 K-tiles/epoch, 3 blocks/CU (R15)
//   softmax over compacted domain; ctx over compacted bf16 rows.

#define NB 32
#define SS 2048
#define HD 1024
#define HE 1024
#define MM (NB * SS)   // compacted (padded) row space
#define NT 32          // K-tiles = HE/32

typedef float f32x4 __attribute__((ext_vector_type(4)));
typedef short bf16x8 __attribute__((ext_vector_type(8)));
typedef short short4v __attribute__((ext_vector_type(4)));

static __device__ __forceinline__ short f2bf(float f) {
    union { __hip_bfloat16 h; short s; } u;
    u.h = __float2bfloat16(f);
    return u.s;
}
static __device__ __forceinline__ float bf2f(short s) {
    union { float f; unsigned u; } u;
    u.u = ((unsigned)(unsigned short)s) << 16;
    return u.f;
}

static __device__ __forceinline__ void gload16(const void* g, const void* l) {
    __builtin_amdgcn_global_load_lds(
        (const __attribute__((address_space(1))) void*)(uintptr_t)(g),
        (__attribute__((address_space(3))) void*)(unsigned)(uintptr_t)(l),
        16, 0, 0);
}

// ---------------- fused front: cvt_enc(+self-scan) | qproj | cvt_wk ----------------
__global__ __launch_bounds__(256) void front_kernel(const int* __restrict__ mask,
                                                    const float* __restrict__ dh,
                                                    const float* __restrict__ Wq,
                                                    const float* __restrict__ Wk,
                                                    const float* __restrict__ enc,
                                                    int* __restrict__ idx,
                                                    int* __restrict__ cnt,
                                                    float* __restrict__ q,
                                                    short* __restrict__ wkb,
                                                    short* __restrict__ encb) {
    const int bid  = blockIdx.x;
    const int tid  = threadIdx.x;
    const int wid  = tid >> 6;
    const int lane = tid & 63;

    if (bid < 4096) {
        // ---- cvt_enc with self-compaction: block = (batch b, window j0..j0+15) ----
        const int b  = bid >> 7;
        const int j0 = (bid & 127) * 16;
        __shared__ int lidx[16];
        __shared__ int lcnt;
        if (wid == 0) {
            if (lane < 16) lidx[lane] = 0;               // pad default
            int base = 0;
            for (int s0 = 0; s0 < SS; s0 += 64) {
                const int m = mask[b * SS + s0 + lane];
                const unsigned long long bal = __ballot(m != 0);
                const int rank = __popcll(bal & ((1ull << lane) - 1ull));
                const int r = base + rank;
                if (m && r >= j0 && r < j0 + 16) lidx[r - j0] = s0 + lane;
                base += (int)__popcll(bal);
            }
            if (lane == 0) lcnt = base;
        }
        __syncthreads();
        const int n  = lcnt;
        const int nr = (n + 127) & ~127;
        // publish idx/cnt for downstream kernels (before any early exit)
        if (tid < 16 && j0 + tid < n) idx[b * SS + j0 + tid] = lidx[tid];
        if (j0 == 0 && tid == 0) cnt[b] = n;
        if (j0 >= nr) return;
        const int j  = j0 + (tid >> 4);
        const int c0 = (tid & 15) * 8;
        short* dst = encb + ((long)b * SS + j) * HE + c0;
        if (j < n) {
            const float* src = enc + ((long)b * SS + lidx[tid >> 4]) * HE + c0;
            #pragma unroll
            for (int u = 0; u < 8; ++u) {
                const f32x4 x = *(const f32x4*)(src + u * 128);
                const f32x4 y = *(const f32x4*)(src + u * 128 + 4);
                bf16x8 o;
                o[0] = f2bf(x[0]); o[1] = f2bf(x[1]); o[2] = f2bf(x[2]); o[3] = f2bf(x[3]);
                o[4] = f2bf(y[0]); o[5] = f2bf(y[1]); o[6] = f2bf(y[2]); o[7] = f2bf(y[3]);
                *(bf16x8*)(dst + u * 128) = o;
            }
        } else {
            const bf16x8 z = (bf16x8){0,0,0,0,0,0,0,0};
            #pragma unroll
            for (int u = 0; u < 8; ++u) *(bf16x8*)(dst + u * 128) = z;
        }
    } else if (bid < 4352) {
        // ---- qproj: one wave per output column d ----
        const int d = (bid - 4096) * 4 + wid;
        const float* wrow = Wq + (long)d * HD + lane * 16;
        f32x4 w0 = *(const f32x4*)(wrow + 0);
        f32x4 w1 = *(const f32x4*)(wrow + 4);
        f32x4 w2 = *(const f32x4*)(wrow + 8);
        f32x4 w3 = *(const f32x4*)(wrow + 12);
        for (int b = 0; b < NB; ++b) {
            const float* drow = dh + b * HD + lane * 16;
            f32x4 d0 = *(const f32x4*)(drow + 0);
            f32x4 d1 = *(const f32x4*)(drow + 4);
            f32x4 d2 = *(const f32x4*)(drow + 8);
            f32x4 d3 = *(const f32x4*)(drow + 12);
            f32x4 s4 = w0 * d0 + w1 * d1 + w2 * d2 + w3 * d3;
            float dot = s4[0] + s4[1] + s4[2] + s4[3];
            #pragma unroll
            for (int off = 32; off > 0; off >>= 1)
                dot += __shfl_xor(dot, off, 64);
            if (lane == 0) q[b * HD + d] = dot;
        }
    } else {
        // ---- cvt_wk: i in [0, 131072) ----
        const int i = (bid - 4352) * 256 + tid;
        const f32x4 a = *(const f32x4*)(Wk + (long)i * 8);
        const f32x4 b = *(const f32x4*)(Wk + (long)i * 8 + 4);
        bf16x8 o;
        o[0] = f2bf(a[0]); o[1] = f2bf(a[1]); o[2] = f2bf(a[2]); o[3] = f2bf(a[3]);
        o[4] = f2bf(b[0]); o[5] = f2bf(b[1]); o[6] = f2bf(b[2]); o[7] = f2bf(b[3]);
        *(bf16x8*)(wkb + (long)i * 8) = o;
    }
}

// ---------------- score GEMM: 128x128, 4 waves, 2 K-tiles per epoch (R15) ----------------
__global__ __launch_bounds__(256, 3) void score_mfma_kernel(const short* __restrict__ encb,
                                                            const short* __restrict__ wkb,
                                                            const float* __restrict__ qv,
                                                            const float* __restrict__ ven,
                                                            const int* __restrict__ cnt,
                                                            float* __restrict__ sp) {
    __shared__ __align__(16) short As[2][4096];   // two 8 KB A K-subtiles
    __shared__ __align__(16) short Bs[2][4096];

    const int bid   = blockIdx.x;
    const int xcd   = bid & 7;
    const int slot  = bid >> 3;                 // 0..511
    const int mtile = xcd * 64 + (slot >> 3);   // 0..511
    const int nt    = slot & 7;                 // 0..7

    const int bb   = mtile >> 4;
    const int tile = mtile & 15;
    if (tile * 128 >= cnt[bb]) return;

    const int tid  = threadIdx.x;
    const int lane = tid & 63;
    const int wid  = tid >> 6;
    const int wr   = wid >> 1;
    const int wc   = wid & 1;
    const long mbase = (long)bb * SS + tile * 128;
    const int  nbase = nt * 128;

    f32x4 acc[4][4];
    #pragma unroll
    for (int m = 0; m < 4; ++m)
        #pragma unroll
        for (int n = 0; n < 4; ++n)
            acc[m][n] = (f32x4){0.f, 0.f, 0.f, 0.f};

    const short* ag0 = encb + (mbase + (tid >> 2)) * (long)HE + (tid & 3) * 8;
    const short* ag1 = ag0 + 64 * (long)HE;
    const short* bg0 = wkb + ((long)(nbase + (tid >> 2))) * HE + (tid & 3) * 8;
    const short* bg1 = bg0 + 64 * (long)HE;

    const int frow = lane & 15;
    const int kby  = (lane >> 4) * 16;

    #define COMPUTE(BUF)                                                         \
        do {                                                                     \
            bf16x8 af[4], bfr[4];                                                \
            _Pragma("unroll")                                                    \
            for (int m = 0; m < 4; ++m)                                          \
                af[m] = *(const bf16x8*)((const char*)As[BUF]                    \
                          + (wr * 64 + m * 16 + frow) * 64 + kby);               \
            _Pragma("unroll")                                                    \
            for (int n = 0; n < 4; ++n)                                          \
                bfr[n] = *(const bf16x8*)((const char*)Bs[BUF]                   \
                          + (wc * 64 + n * 16 + frow) * 64 + kby);               \
            _Pragma("unroll")                                                    \
            for (int m = 0; m < 4; ++m)                                          \
                _Pragma("unroll")                                                \
                for (int n = 0; n < 4; ++n)                                      \
                    acc[m][n] = __builtin_amdgcn_mfma_f32_16x16x32_bf16(         \
                        af[m], bfr[n], acc[m][n], 0, 0, 0);                      \
        } while (0)

    for (int kt = 0; kt < NT; kt += 2) {
        const int ko0 = kt * 32;
        const int ko1 = ko0 + 32;
        gload16(ag0 + ko0, (char*)As[0] + wid * 1024);
        gload16(ag1 + ko0, (char*)As[0] + 4096 + wid * 1024);
        gload16(bg0 + ko0, (char*)Bs[0] + wid * 1024);
        gload16(bg1 + ko0, (char*)Bs[0] + 4096 + wid * 1024);
        gload16(ag0 + ko1, (char*)As[1] + wid * 1024);
        gload16(ag1 + ko1, (char*)As[1] + 4096 + wid * 1024);
        gload16(bg0 + ko1, (char*)Bs[1] + wid * 1024);
        gload16(bg1 + ko1, (char*)Bs[1] + 4096 + wid * 1024);
        __syncthreads();
        COMPUTE(0);
        COMPUTE(1);
        __syncthreads();
    }
    #undef COMPUTE

    float qq[4], vv[4];
    #pragma unroll
    for (int n = 0; n < 4; ++n) {
        const int c = nbase + wc * 64 + n * 16 + frow;
        qq[n] = qv[bb * HD + c];
        vv[n] = ven[c];
    }
    float p[4][4];
    #pragma unroll
    for (int m = 0; m < 4; ++m) {
        #pragma unroll
        for (int rg = 0; rg < 4; ++rg) {
            float s = 0.f;
            #pragma unroll
            for (int n = 0; n < 4; ++n) {
                const float x = acc[m][n][rg] + qq[n];
                const float e = __expf(2.f * x);
                const float t = 1.f - 2.f * __builtin_amdgcn_rcpf(e + 1.f);
                s += vv[n] * t;
            }
            #pragma unroll
            for (int msk = 1; msk <= 8; msk <<= 1)
                s += __shfl_xor(s, msk, 64);
            p[m][rg] = s;
        }
    }
    if ((lane & 15) == 0) {
        const int g = lane >> 4;
        float* dst = sp + (long)(nt * 2 + wc) * MM;
        #pragma unroll
        for (int m = 0; m < 4; ++m)
            #pragma unroll
            for (int rg = 0; rg < 4; ++rg)
                dst[mbase + wr * 64 + m * 16 + g * 4 + rg] = p[m][rg];
    }
}

// ---------------- softmax over compacted domain; zero + scatter to attn ----------------
__global__ __launch_bounds__(256) void softmax_kernel(const float* __restrict__ sp,
                                                      const int* __restrict__ idx,
                                                      const int* __restrict__ cnt,
                                                      float* __restrict__ attn,
                                                      float* __restrict__ wcomp) {
    const int b = blockIdx.x;
    const int tid = threadIdx.x;
    const int lane = tid & 63;
    const int wid = tid >> 6;
    const int n = cnt[b];
    #pragma unroll
    for (int i = 0; i < 8; ++i)
        attn[b * SS + tid + i * 256] = 0.f;
    __shared__ float red[4];
    float sc[8];
    float mx = -3.0e38f;
    #pragma unroll
    for (int i = 0; i < 8; ++i) {
        const int j = tid + i * 256;
        float v = -3.0e38f;
        if (j < n) {
            v = 0.f;
            #pragma unroll
            for (int k = 0; k < 16; ++k)
                v += sp[(long)k * MM + b * SS + j];
        }
        sc[i] = v;
        mx = fmaxf(mx, v);
    }
    #pragma unroll
    for (int off = 32; off > 0; off >>= 1)
        mx = fmaxf(mx, __shfl_xor(mx, off, 64));
    if (lane == 0) red[wid] = mx;
    __syncthreads();
    mx = fmaxf(fmaxf(red[0], red[1]), fmaxf(red[2], red[3]));
    __syncthreads();
    float sum = 0.f;
    #pragma unroll
    for (int i = 0; i < 8; ++i) {
        const float e = (sc[i] > -1.0e38f) ? __expf(sc[i] - mx) : 0.f;
        sc[i] = e;
        sum += e;
    }
    #pragma unroll
    for (int off = 32; off > 0; off >>= 1)
        sum += __shfl_xor(sum, off, 64);
    if (lane == 0) red[wid] = sum;
    __syncthreads();
    sum = red[0] + red[1] + red[2] + red[3];
    const float inv = 1.f / sum;
    #pragma unroll
    for (int i = 0; i < 8; ++i) {
        const int j = tid + i * 256;
        const float w = sc[i] * inv;
        wcomp[b * SS + j] = w;
        if (j < n) attn[b * SS + idx[b * SS + j]] = w;
    }
}

// ---------------- context over compacted bf16 rows ----------------
__global__ __launch_bounds__(256) void ctx_partial_kernel(const short* __restrict__ encb,
                                                          const float* __restrict__ wcomp,
                                                          const int* __restrict__ cnt,
                                                          float* __restrict__ cp) {
    const int b = blockIdx.x >> 5;
    const int chunk = blockIdx.x & 31;
    const int tid = threadIdx.x;
    float* dst = cp + ((long)(b * 32 + chunk)) * HE + tid * 4;
    if (chunk * 64 >= cnt[b]) {
        *(f32x4*)dst = (f32x4){0.f, 0.f, 0.f, 0.f};
        return;
    }
    const short* ep = encb + ((long)b * SS + chunk * 64) * HE + tid * 4;
    const float* ap = wcomp + b * SS + chunk * 64;
    f32x4 acc = (f32x4){0.f, 0.f, 0.f, 0.f};
    #pragma unroll 4
    for (int s = 0; s < 64; ++s) {
        const float w = ap[s];
        const short4v v = *(const short4v*)(ep + (long)s * HE);
        acc[0] += w * bf2f(v[0]);
        acc[1] += w * bf2f(v[1]);
        acc[2] += w * bf2f(v[2]);
        acc[3] += w * bf2f(v[3]);
    }
    *(f32x4*)dst = acc;
}

__global__ __launch_bounds__(256) void ctx_reduce_kernel(const float* __restrict__ cp,
                                                         float* __restrict__ out) {
    const int o = blockIdx.x * 256 + threadIdx.x;
    const int b = o >> 10;
    const int e = o & 1023;
    float s = 0.f;
    #pragma unroll
    for (int c = 0; c < 32; ++c)
        s += cp[((long)(b * 32 + c)) * HE + e];
    out[o] = s;
}

extern "C" void kernel_launch(void* const* d_in, const int* in_sizes, int n_in,
                              void* d_out, int out_size, void* d_ws, size_t ws_size,
                              hipStream_t stream) {
    const float* dh   = (const float*)d_in[0];
    const float* enc  = (const float*)d_in[1];
    const int*   mask = (const int*)d_in[2];
    const float* Wq   = (const float*)d_in[3];
    const float* Wk   = (const float*)d_in[4];
    const float* Ve   = (const float*)d_in[5];

    float* out  = (float*)d_out;
    float* ctx  = out;
    float* attn = out + NB * HD;

    float* ws    = (float*)d_ws;
    float* wq_   = ws;                            // 32768 f
    float* sp    = ws + 32768;                    // 16 * 65536 f (4 MB)
    float* cp    = sp + 16 * (long)MM;            // 32*32*1024 f (4 MB)
    short* wkb   = (short*)(cp + 32 * 32 * HE);   // 1M bf16 (2 MB)
    float* wcomp = (float*)(wkb + (long)HD * HE); // 65536 f
    int*   idx   = (int*)(wcomp + MM);            // 65536 i
    int*   cnt   = idx + MM;                      // 32 i (+pad)
    short* encb  = (short*)(cnt + 64);            // 67.1M bf16 (128 MB)

    front_kernel<<<4864, 256, 0, stream>>>(mask, dh, Wq, Wk, enc,
                                           idx, cnt, wq_, wkb, encb);
    score_mfma_kernel<<<4096, 256, 0, stream>>>(encb, wkb, wq_, Ve, cnt, sp);
    softmax_kernel<<<NB, 256, 0, stream>>>(sp, idx, cnt, attn, wcomp);
    ctx_partial_kernel<<<1024, 256, 0, stream>>>(encb, wcomp, cnt, cp);
    ctx_reduce_kernel<<<128, 256, 0, stream>>>(cp, ctx);
}